// Round 3
// baseline (675.497 us; speedup 1.0000x reference)
//
#include <hip/hip_runtime.h>
#include <math.h>

#define IH 2048
#define IW 2048
#define NBATCH 8
#define TW 64            // tile width  (output)
#define TH 32            // tile height (output)
#define HALO 3
#define SR (TH + 2*HALO) // 38 staged rows
#define SROW 72          // padded row stride (floats) for s_img
#define ACT_TH 0.1f
#define IMP_TH 0.1f
#define TILES_PER_BATCH ((IW / TW) * (IH / TH))   // 32*64 = 2048

// 1D Gaussian taps, sigma = 7/6, normalized.
#define G0 0.0125602013f
#define G1 0.0788279697f
#define G2 0.2372960895f
#define G3 0.3426314790f

// ---------------- Kernel 1: per-batch max --------------------------------
// 128 blocks x 256 threads per batch -> 32768 threads, 32 float4 each
// (exactly 2048*2048/4). Unroll-4 keeps 4 loads in flight per wave.
__global__ __launch_bounds__(256) void batch_max_kernel(
    const float* __restrict__ x, unsigned int* __restrict__ maxbits)
{
    const int b = blockIdx.y;
    const float4* p = (const float4*)(x + (size_t)b * (size_t)(IH * IW));
    const int t = blockIdx.x * 256 + threadIdx.x;    // 0..32767
    float m0 = 0.0f, m1 = 0.0f, m2 = 0.0f, m3 = 0.0f;
    for (int j = 0; j < 32; j += 4) {
        float4 a = p[t + (size_t)(j + 0) * 32768];
        float4 c = p[t + (size_t)(j + 1) * 32768];
        float4 d = p[t + (size_t)(j + 2) * 32768];
        float4 e = p[t + (size_t)(j + 3) * 32768];
        m0 = fmaxf(m0, fmaxf(fmaxf(a.x, a.y), fmaxf(a.z, a.w)));
        m1 = fmaxf(m1, fmaxf(fmaxf(c.x, c.y), fmaxf(c.z, c.w)));
        m2 = fmaxf(m2, fmaxf(fmaxf(d.x, d.y), fmaxf(d.z, d.w)));
        m3 = fmaxf(m3, fmaxf(fmaxf(e.x, e.y), fmaxf(e.z, e.w)));
    }
    float m = fmaxf(fmaxf(m0, m1), fmaxf(m2, m3));
#pragma unroll
    for (int s = 1; s < 64; s <<= 1) m = fmaxf(m, __shfl_xor(m, s));
    __shared__ float sm[4];
    const int lane = threadIdx.x & 63, wv = threadIdx.x >> 6;
    if (lane == 0) sm[wv] = m;
    __syncthreads();
    if (threadIdx.x == 0) {
        m = fmaxf(fmaxf(sm[0], sm[1]), fmaxf(sm[2], sm[3]));
        // x >= 0, so uint-bit compare == float compare
        atomicMax(&maxbits[b], __float_as_uint(m));
    }
}

// ---------------- Kernel 2: fused normalize + block stats + finish -------
// 64x32 output tile per WG. LDS ~30.5KB -> 5 WG/CU (20 waves/CU).
__global__ __launch_bounds__(256, 5) void piqe_main_kernel(
    const float* __restrict__ x, const unsigned int* __restrict__ maxbits,
    float* __restrict__ contrib_sum, unsigned int* __restrict__ nhsa,
    unsigned int* __restrict__ done_cnt, float* __restrict__ out)
{
    __shared__ float s_img[SR * SROW];   // 38x72 img; later MSCN n in-place
    __shared__ float s_mu[SR * TW];      // horizontal conv of img   (38x64)
    __shared__ float s_mu2[SR * TW];     // horizontal conv of img^2 (38x64)
    __shared__ float s_c;
    __shared__ unsigned int s_a;

    const int tid = threadIdx.x;
    const int b = blockIdx.z;
    const int ox = blockIdx.x * TW;
    const int oy = blockIdx.y * TH;
    const float* img0 = x + (size_t)b * (size_t)(IH * IW);
    const float scale = 255.0f / __uint_as_float(maxbits[b]);

    if (tid == 0) { s_c = 0.0f; s_a = 0u; }

    // ---- Phase A: load 38x70 halo tile (edge-clamped), img = rint(x*scale)
    {
        const int c4 = (tid & 15) << 2;           // 0,4,...,60
        for (int r = tid >> 4; r < SR; r += 16) { // 16 rows/pass
            int gy = oy + r - HALO; gy = max(0, min(IH - 1, gy));
            float4 vv = *(const float4*)(img0 + (size_t)gy * IW + ox + c4);
            float* d = &s_img[r * SROW + HALO + c4];
            d[0] = rintf(vv.x * scale);
            d[1] = rintf(vv.y * scale);
            d[2] = rintf(vv.z * scale);
            d[3] = rintf(vv.w * scale);
        }
        const int hc = tid & 7;                   // halo cols, 6 used
        if (hc < 6) {
            int col = (hc < 3) ? hc : 64 + hc;                 // 0,1,2,67,68,69
            int gx = (hc < 3) ? (ox - 3 + hc) : (ox + 61 + hc);
            gx = max(0, min(IW - 1, gx));
            for (int r = tid >> 3; r < SR; r += 32) {
                int gy = oy + r - HALO; gy = max(0, min(IH - 1, gy));
                s_img[r * SROW + col] = rintf(img0[(size_t)gy * IW + gx] * scale);
            }
        }
    }
    __syncthreads();

    const float gk[7] = {G0, G1, G2, G3, G2, G1, G0};

    // ---- Phase B: horizontal 7-tap (img, img^2) -> s_mu/s_mu2 (38x64)
    // 16 threads/row, 4 output cols each. b128 at float offset 72r+4c:
    // every 8-lane phase group covers a full 32-bank sweep -> conflict-free.
    {
        const int c4 = (tid & 15) << 2;
        for (int r = tid >> 4; r < SR; r += 16) {
            const float* p = &s_img[r * SROW + c4];   // 16B aligned
            float v[10];
            *(float4*)(v)     = *(const float4*)(p);
            *(float4*)(v + 4) = *(const float4*)(p + 4);
            *(float2*)(v + 8) = *(const float2*)(p + 8);
            float q[10];
#pragma unroll
            for (int i = 0; i < 10; ++i) q[i] = v[i] * v[i];
            float om[4], om2[4];
#pragma unroll
            for (int j = 0; j < 4; ++j) {
                float m = 0.0f, m2 = 0.0f;
#pragma unroll
                for (int k = 0; k < 7; ++k) {
                    m  = fmaf(gk[k], v[j + k], m);
                    m2 = fmaf(gk[k], q[j + k], m2);
                }
                om[j] = m; om2[j] = m2;
            }
            *(float4*)&s_mu [r * TW + c4] = *(const float4*)(om);
            *(float4*)&s_mu2[r * TW + c4] = *(const float4*)(om2);
        }
    }
    __syncthreads();

    // ---- Phase C: vertical 7-tap, n = (img-mu)/(std+1) in-place in s_img.
    // thread = (col = tid&63, run of 8 rows); stride-1 lanes -> conflict-free.
    {
        const int c = tid & 63;
        const int r0 = (tid >> 6) * 8;
        float mv[14], mv2[14];
#pragma unroll
        for (int i = 0; i < 14; ++i) {
            mv[i]  = s_mu [(r0 + i) * TW + c];
            mv2[i] = s_mu2[(r0 + i) * TW + c];
        }
#pragma unroll
        for (int i = 0; i < 8; ++i) {
            float m = 0.0f, m2 = 0.0f;
#pragma unroll
            for (int k = 0; k < 7; ++k) {
                m  = fmaf(gk[k], mv[i + k], m);
                m2 = fmaf(gk[k], mv2[i + k], m2);
            }
            float sd = __builtin_amdgcn_sqrtf(fabsf(m2 - m * m));
            int ii = (r0 + i + HALO) * SROW + (c + HALO);
            float pix = s_img[ii];
            s_img[ii] = (pix - m) * __builtin_amdgcn_rcpf(sd + 1.0f);
        }
    }
    __syncthreads();

    // ---- Phase D: per-16x16-block stats. 8 blocks; 32-lane team per block;
    // lane = (row = t&15, col half = t>>4, 8 cols each).
    {
        const int t = tid & 31;
        const int team = tid >> 5;             // 0..7
        const int bi = team >> 2, bj = team & 3;
        const int row = t & 15, half = t >> 4;
        const float* np0 = &s_img[(HALO + bi * 16) * SROW + (HALO + bj * 16)];
        const float* pr = np0 + row * SROW + half * 8;
        float rv[8];
#pragma unroll
        for (int k = 0; k < 8; ++k) rv[k] = pr[k];
        float s1 = 0.0f, s2 = 0.0f;
#pragma unroll
        for (int k = 0; k < 8; ++k) { s1 += rv[k]; s2 += rv[k] * rv[k]; }
        float ce = half ? rv[0] : rv[7];       // center cols {7,8}
        float c1 = ce, c2 = ce * ce;
        float ex = half ? rv[1] : rv[7];       // sur excludes cols {7,9}
        float u1 = s1 - ex, u2 = s2 - ex * ex;

        // Edge 11-window seg-std minima: lanes 0..3 of each team, one edge each
        float minstd = __builtin_inff();
        if (t < 4) {
            int offs, stp;
            if (t == 0)      { offs = 0;         stp = 1; }     // top
            else if (t == 1) { offs = 15 * SROW; stp = 1; }     // bottom
            else if (t == 2) { offs = 0;         stp = SROW; }  // left
            else             { offs = 15;        stp = SROW; }  // right
            float e[16];
#pragma unroll
            for (int k = 0; k < 16; ++k) e[k] = np0[offs + k * stp];
            float w1 = 0.0f, w2 = 0.0f;
#pragma unroll
            for (int k = 0; k < 6; ++k) { w1 += e[k]; w2 += e[k] * e[k]; }
#pragma unroll
            for (int i = 0; i < 11; ++i) {
                float var = (w2 - w1 * w1 * (1.0f / 6.0f)) * (1.0f / 5.0f);
                minstd = fminf(minstd,
                               __builtin_amdgcn_sqrtf(fmaxf(var, 0.0f)));
                if (i < 10) {
                    w1 += e[i + 6] - e[i];
                    w2 += e[i + 6] * e[i + 6] - e[i] * e[i];
                }
            }
        }

        // Butterfly reduction within each 32-lane team
#pragma unroll
        for (int m = 1; m < 32; m <<= 1) {
            s1 += __shfl_xor(s1, m);
            s2 += __shfl_xor(s2, m);
            c1 += __shfl_xor(c1, m);
            c2 += __shfl_xor(c2, m);
            u1 += __shfl_xor(u1, m);
            u2 += __shfl_xor(u2, m);
            minstd = fminf(minstd, __shfl_xor(minstd, m));
        }

        if (t == 0) {
            float bv = fmaxf((s2 - s1 * s1 * (1.0f / 256.0f)) * (1.0f / 255.0f), 0.0f);
            bool active = bv > ACT_TH;
            float cstd = __builtin_amdgcn_sqrtf(
                fmaxf((c2 - c1 * c1 * (1.0f / 32.0f)) * (1.0f / 31.0f), 0.0f));
            float sstd = __builtin_amdgcn_sqrtf(
                fmaxf((u2 - u1 * u1 * (1.0f / 224.0f)) * (1.0f / 223.0f), 0.0f));
            float csd = cstd / sstd;            // 0/0 -> NaN (matches ref)
            if (csd != csd) csd = 0.0f;
            float sigma = __builtin_amdgcn_sqrtf(bv);
            float beta = fabsf(sigma - csd) / fmaxf(sigma, csd);
            bool wnc = sigma > 2.0f * beta;     // NaN beta -> false (matches)
            bool impaired = minstd < IMP_TH;
            if (active) {
                float contrib = (impaired ? (1.0f - bv) : 0.0f) + (wnc ? bv : 0.0f);
                atomicAdd(&s_c, contrib);
                atomicAdd(&s_a, 1u);
            }
        }
    }
    __syncthreads();
    if (tid == 0) {
        atomicAdd(&contrib_sum[b], s_c);
        atomicAdd(&nhsa[b], s_a);
        __threadfence();                         // publish before done-count
        unsigned int old = atomicAdd(&done_cnt[b], 1u);
        if (old == TILES_PER_BATCH - 1) {
            // atomic reads: coherent point, immune to stale per-XCD L2 lines
            float cs = atomicAdd(&contrib_sum[b], 0.0f);
            unsigned int na = atomicAdd(&nhsa[b], 0u);
            out[b] = (cs + 1.0f) / (1.0f + (float)na) * 100.0f;
        }
    }
}

extern "C" void kernel_launch(void* const* d_in, const int* in_sizes, int n_in,
                              void* d_out, int out_size, void* d_ws, size_t ws_size,
                              hipStream_t stream)
{
    const float* x = (const float*)d_in[0];
    float* out = (float*)d_out;

    unsigned int* maxbits = (unsigned int*)d_ws;                 // 8 u32 @ 0
    float* contrib = (float*)((char*)d_ws + 32);                 // 8 f32 @ 32
    unsigned int* nhsa = (unsigned int*)((char*)d_ws + 64);      // 8 u32 @ 64
    unsigned int* done = (unsigned int*)((char*)d_ws + 96);      // 8 u32 @ 96

    hipMemsetAsync(d_ws, 0, 128, stream);
    batch_max_kernel<<<dim3(128, NBATCH), 256, 0, stream>>>(x, maxbits);
    piqe_main_kernel<<<dim3(IW / TW, IH / TH, NBATCH), 256, 0, stream>>>(
        x, maxbits, contrib, nhsa, done, out);
}

// Round 4
// 419.110 us; speedup vs baseline: 1.6117x; 1.6117x over previous
//
#include <hip/hip_runtime.h>
#include <math.h>

#define IH 2048
#define IW 2048
#define NBATCH 8
#define TW 64            // tile width  (output)
#define TH 32            // tile height (output)
#define HALO 3
#define SR (TH + 2*HALO) // 38 staged rows
#define SROW 72          // s_img row stride (floats); layout: L = gcol-ox+4
#define ACT_TH 0.1f
#define IMP_TH 0.1f

// 1D Gaussian taps, sigma = 7/6, normalized.
#define G0 0.0125602013f
#define G1 0.0788279697f
#define G2 0.2372960895f
#define G3 0.3426314790f

// ---------------- Kernel 1: per-batch max --------------------------------
// 128 blocks x 256 threads per batch; unroll-4 keeps 4 loads in flight.
__global__ __launch_bounds__(256) void batch_max_kernel(
    const float* __restrict__ x, unsigned int* __restrict__ maxbits)
{
    const int b = blockIdx.y;
    const float4* p = (const float4*)(x + (size_t)b * (size_t)(IH * IW));
    const int t = blockIdx.x * 256 + threadIdx.x;    // 0..32767
    float m0 = 0.0f, m1 = 0.0f, m2 = 0.0f, m3 = 0.0f;
    for (int j = 0; j < 32; j += 4) {
        float4 a = p[t + (size_t)(j + 0) * 32768];
        float4 c = p[t + (size_t)(j + 1) * 32768];
        float4 d = p[t + (size_t)(j + 2) * 32768];
        float4 e = p[t + (size_t)(j + 3) * 32768];
        m0 = fmaxf(m0, fmaxf(fmaxf(a.x, a.y), fmaxf(a.z, a.w)));
        m1 = fmaxf(m1, fmaxf(fmaxf(c.x, c.y), fmaxf(c.z, c.w)));
        m2 = fmaxf(m2, fmaxf(fmaxf(d.x, d.y), fmaxf(d.z, d.w)));
        m3 = fmaxf(m3, fmaxf(fmaxf(e.x, e.y), fmaxf(e.z, e.w)));
    }
    float m = fmaxf(fmaxf(m0, m1), fmaxf(m2, m3));
#pragma unroll
    for (int s = 1; s < 64; s <<= 1) m = fmaxf(m, __shfl_xor(m, s));
    __shared__ float sm[4];
    const int lane = threadIdx.x & 63, wv = threadIdx.x >> 6;
    if (lane == 0) sm[wv] = m;
    __syncthreads();
    if (threadIdx.x == 0) {
        m = fmaxf(fmaxf(sm[0], sm[1]), fmaxf(sm[2], sm[3]));
        atomicMax(&maxbits[b], __float_as_uint(m));   // x>=0: bit cmp == fp cmp
    }
}

// ---------------- Kernel 2: fused normalize + block stats ----------------
// 64x32 tile, ~30.5KB LDS -> 5 WG/CU (20 waves).
// LDS col L = gcol - ox + 4; interior L=4..67 (16B aligned), halo L=1..3,68..70.
// All b128 accesses use 4-float lane spacing: every 8-lane phase group sweeps
// all 32 banks (row stride 72 == 8 mod 32 chains the sweep across rows).
__global__ __launch_bounds__(256, 5) void piqe_main_kernel(
    const float* __restrict__ x, const unsigned int* __restrict__ maxbits,
    float* __restrict__ contrib_sum, unsigned int* __restrict__ nhsa)
{
    __shared__ float s_img[SR * SROW];   // 38x72; later MSCN n in-place
    __shared__ float s_mu[SR * TW];      // horiz conv of img   (38x64)
    __shared__ float s_mu2[SR * TW];     // horiz conv of img^2 (38x64)
    __shared__ float s_c;
    __shared__ unsigned int s_a;

    const int tid = threadIdx.x;
    const int b = blockIdx.z;
    const int ox = blockIdx.x * TW;
    const int oy = blockIdx.y * TH;
    const float* img0 = x + (size_t)b * (size_t)(IH * IW);
    const float scale = 255.0f / __uint_as_float(maxbits[b]);

    if (tid == 0) { s_c = 0.0f; s_a = 0u; }

    // ---- Phase A: stage tile. Interior: float4 global -> b128 LDS store.
    {
        const int c = tid & 15;                    // f4 col, gcol ox+4c..+3
        for (int r = tid >> 4; r < SR; r += 16) {
            int gy = oy + r - HALO; gy = max(0, min(IH - 1, gy));
            float4 vv = *(const float4*)(img0 + (size_t)gy * IW + ox + 4 * c);
            float4 w;
            w.x = rintf(vv.x * scale);
            w.y = rintf(vv.y * scale);
            w.z = rintf(vv.z * scale);
            w.w = rintf(vv.w * scale);
            *(float4*)&s_img[r * SROW + 4 + 4 * c] = w;   // L=4+4c, aligned
        }
        const int hc = tid & 7;                    // 6 halo cols, scalar
        if (hc < 6) {
            int Lc = (hc < 3) ? (1 + hc) : (65 + hc);          // 1,2,3,68,69,70
            int gx = (hc < 3) ? (ox - 3 + hc) : (ox + 61 + hc); // clamp at edges
            gx = max(0, min(IW - 1, gx));
            for (int r = tid >> 3; r < SR; r += 32) {
                int gy = oy + r - HALO; gy = max(0, min(IH - 1, gy));
                s_img[r * SROW + Lc] = rintf(img0[(size_t)gy * IW + gx] * scale);
            }
        }
    }
    __syncthreads();

    const float gk[7] = {G0, G1, G2, G3, G2, G1, G0};

    // ---- Phase B: horizontal 7-tap (img, img^2) -> s_mu/s_mu2 (38x64)
    // 16 threads/row, 4 outputs each; 3 aligned b128 reads cover L c4..c4+11;
    // window for output col c4+j is v[1+j .. 7+j].
    {
        const int c4 = (tid & 15) << 2;
        for (int r = tid >> 4; r < SR; r += 16) {
            const float* p = &s_img[r * SROW + c4];
            float v[12];
            *(float4*)(v)     = *(const float4*)(p);
            *(float4*)(v + 4) = *(const float4*)(p + 4);
            *(float4*)(v + 8) = *(const float4*)(p + 8);
            float q[11];
#pragma unroll
            for (int i = 1; i < 11; ++i) q[i] = v[i] * v[i];
            float om[4], om2[4];
#pragma unroll
            for (int j = 0; j < 4; ++j) {
                float m = 0.0f, m2 = 0.0f;
#pragma unroll
                for (int k = 0; k < 7; ++k) {
                    m  = fmaf(gk[k], v[1 + j + k], m);
                    m2 = fmaf(gk[k], q[1 + j + k], m2);
                }
                om[j] = m; om2[j] = m2;
            }
            *(float4*)&s_mu [r * TW + c4] = *(const float4*)(om);
            *(float4*)&s_mu2[r * TW + c4] = *(const float4*)(om2);
        }
    }
    __syncthreads();

    // ---- Phase C: vertical 7-tap, n = (img-mu)/(std+1) in-place in s_img.
    // thread = (col c = tid&63, 8-row run); stride-1 lanes -> conflict-free.
    {
        const int c = tid & 63;
        const int r0 = (tid >> 6) * 8;
        float mv[14], mv2[14];
#pragma unroll
        for (int i = 0; i < 14; ++i) {
            mv[i]  = s_mu [(r0 + i) * TW + c];
            mv2[i] = s_mu2[(r0 + i) * TW + c];
        }
#pragma unroll
        for (int i = 0; i < 8; ++i) {
            float m = 0.0f, m2 = 0.0f;
#pragma unroll
            for (int k = 0; k < 7; ++k) {
                m  = fmaf(gk[k], mv[i + k], m);
                m2 = fmaf(gk[k], mv2[i + k], m2);
            }
            float sd = __builtin_amdgcn_sqrtf(fabsf(m2 - m * m));
            int ii = (r0 + i + HALO) * SROW + (c + 4);
            float pix = s_img[ii];
            s_img[ii] = (pix - m) * __builtin_amdgcn_rcpf(sd + 1.0f);
        }
    }
    __syncthreads();

    // ---- Phase D: per-16x16-block stats. 8 blocks; 32-lane team per block;
    // lane = (row = t>>1, half = t&1): 2 aligned b128 per lane, worst 2-way.
    {
        const int t = tid & 31;
        const int team = tid >> 5;             // 0..7
        const int bi = team >> 2, bj = team & 3;
        const int row = t >> 1, half = t & 1;
        const float* np0 = &s_img[(HALO + bi * 16) * SROW + (bj * 16 + 4)];
        const float* pr = np0 + row * SROW + half * 8;
        float rv[8];
        *(float4*)(rv)     = *(const float4*)(pr);
        *(float4*)(rv + 4) = *(const float4*)(pr + 4);
        float s1 = 0.0f, s2 = 0.0f;
#pragma unroll
        for (int k = 0; k < 8; ++k) { s1 += rv[k]; s2 += rv[k] * rv[k]; }
        float ce = half ? rv[0] : rv[7];       // center cols {7,8}
        float c1 = ce, c2 = ce * ce;
        float ex = half ? rv[1] : rv[7];       // sur excludes cols {7,9}
        float u1 = s1 - ex, u2 = s2 - ex * ex;

        // Edge 11-window seg-std minima: lanes 0..3 of each team, one edge each
        float minstd = __builtin_inff();
        if (t < 4) {
            int offs, stp;
            if (t == 0)      { offs = 0;         stp = 1; }     // top
            else if (t == 1) { offs = 15 * SROW; stp = 1; }     // bottom
            else if (t == 2) { offs = 0;         stp = SROW; }  // left
            else             { offs = 15;        stp = SROW; }  // right
            float e[16];
#pragma unroll
            for (int k = 0; k < 16; ++k) e[k] = np0[offs + k * stp];
            float w1 = 0.0f, w2 = 0.0f;
#pragma unroll
            for (int k = 0; k < 6; ++k) { w1 += e[k]; w2 += e[k] * e[k]; }
#pragma unroll
            for (int i = 0; i < 11; ++i) {
                float var = (w2 - w1 * w1 * (1.0f / 6.0f)) * (1.0f / 5.0f);
                minstd = fminf(minstd,
                               __builtin_amdgcn_sqrtf(fmaxf(var, 0.0f)));
                if (i < 10) {
                    w1 += e[i + 6] - e[i];
                    w2 += e[i + 6] * e[i + 6] - e[i] * e[i];
                }
            }
        }

        // Butterfly reduction within each 32-lane team
#pragma unroll
        for (int m = 1; m < 32; m <<= 1) {
            s1 += __shfl_xor(s1, m);
            s2 += __shfl_xor(s2, m);
            c1 += __shfl_xor(c1, m);
            c2 += __shfl_xor(c2, m);
            u1 += __shfl_xor(u1, m);
            u2 += __shfl_xor(u2, m);
            minstd = fminf(minstd, __shfl_xor(minstd, m));
        }

        if (t == 0) {
            float bv = fmaxf((s2 - s1 * s1 * (1.0f / 256.0f)) * (1.0f / 255.0f), 0.0f);
            bool active = bv > ACT_TH;
            float cstd = __builtin_amdgcn_sqrtf(
                fmaxf((c2 - c1 * c1 * (1.0f / 32.0f)) * (1.0f / 31.0f), 0.0f));
            float sstd = __builtin_amdgcn_sqrtf(
                fmaxf((u2 - u1 * u1 * (1.0f / 224.0f)) * (1.0f / 223.0f), 0.0f));
            float csd = cstd / sstd;            // 0/0 -> NaN (matches ref)
            if (csd != csd) csd = 0.0f;
            float sigma = __builtin_amdgcn_sqrtf(bv);
            float beta = fabsf(sigma - csd) / fmaxf(sigma, csd);
            bool wnc = sigma > 2.0f * beta;     // NaN beta -> false (matches)
            bool impaired = minstd < IMP_TH;
            if (active) {
                float contrib = (impaired ? (1.0f - bv) : 0.0f) + (wnc ? bv : 0.0f);
                atomicAdd(&s_c, contrib);
                atomicAdd(&s_a, 1u);
            }
        }
    }
    __syncthreads();
    if (tid == 0) {
        atomicAdd(&contrib_sum[b], s_c);
        atomicAdd(&nhsa[b], s_a);
    }
}

// ---------------- Kernel 3: final score ----------------------------------
__global__ void piqe_finish_kernel(const float* __restrict__ contrib_sum,
                                   const unsigned int* __restrict__ nhsa,
                                   float* __restrict__ out)
{
    int b = threadIdx.x;
    if (b < NBATCH)
        out[b] = (contrib_sum[b] + 1.0f) / (1.0f + (float)nhsa[b]) * 100.0f;
}

extern "C" void kernel_launch(void* const* d_in, const int* in_sizes, int n_in,
                              void* d_out, int out_size, void* d_ws, size_t ws_size,
                              hipStream_t stream)
{
    const float* x = (const float*)d_in[0];
    float* out = (float*)d_out;

    unsigned int* maxbits = (unsigned int*)d_ws;                 // 8 u32 @ 0
    float* contrib = (float*)((char*)d_ws + 32);                 // 8 f32 @ 32
    unsigned int* nhsa = (unsigned int*)((char*)d_ws + 64);      // 8 u32 @ 64

    hipMemsetAsync(d_ws, 0, 96, stream);
    batch_max_kernel<<<dim3(128, NBATCH), 256, 0, stream>>>(x, maxbits);
    piqe_main_kernel<<<dim3(IW / TW, IH / TH, NBATCH), 256, 0, stream>>>(
        x, maxbits, contrib, nhsa);
    piqe_finish_kernel<<<1, 64, 0, stream>>>(contrib, nhsa, out);
}

// Round 5
// 416.535 us; speedup vs baseline: 1.6217x; 1.0062x over previous
//
#include <hip/hip_runtime.h>
#include <math.h>

#define IH 2048
#define IW 2048
#define NBATCH 8
#define TW 64            // tile width  (output)
#define TH 32            // tile height (output)
#define HALO 3
#define SR (TH + 2*HALO) // 38 staged rows
#define SROW 72          // s_img row stride (floats); L = gcol-ox+4
#define MROW 128         // s_m row stride (floats): 32 float4 (mu,mu2 pairs)
#define ACT_TH 0.1f
#define IMP_TH 0.1f

// 1D Gaussian taps, sigma = 7/6, normalized.
#define G0 0.0125602013f
#define G1 0.0788279697f
#define G2 0.2372960895f
#define G3 0.3426314790f

// ---------------- Kernel 1: per-batch max --------------------------------
// 256 blocks x 256 threads per batch (8 WG/CU); 16 f4/thread, unroll 4.
__global__ __launch_bounds__(256) void batch_max_kernel(
    const float* __restrict__ x, unsigned int* __restrict__ maxbits)
{
    const int b = blockIdx.y;
    const float4* p = (const float4*)(x + (size_t)b * (size_t)(IH * IW));
    const int t = blockIdx.x * 256 + threadIdx.x;    // 0..65535
    float m0 = 0.0f, m1 = 0.0f, m2 = 0.0f, m3 = 0.0f;
    for (int j = 0; j < 16; j += 4) {
        float4 a = p[t + (size_t)(j + 0) * 65536];
        float4 c = p[t + (size_t)(j + 1) * 65536];
        float4 d = p[t + (size_t)(j + 2) * 65536];
        float4 e = p[t + (size_t)(j + 3) * 65536];
        m0 = fmaxf(m0, fmaxf(fmaxf(a.x, a.y), fmaxf(a.z, a.w)));
        m1 = fmaxf(m1, fmaxf(fmaxf(c.x, c.y), fmaxf(c.z, c.w)));
        m2 = fmaxf(m2, fmaxf(fmaxf(d.x, d.y), fmaxf(d.z, d.w)));
        m3 = fmaxf(m3, fmaxf(fmaxf(e.x, e.y), fmaxf(e.z, e.w)));
    }
    float m = fmaxf(fmaxf(m0, m1), fmaxf(m2, m3));
#pragma unroll
    for (int s = 1; s < 64; s <<= 1) m = fmaxf(m, __shfl_xor(m, s));
    __shared__ float sm[4];
    const int lane = threadIdx.x & 63, wv = threadIdx.x >> 6;
    if (lane == 0) sm[wv] = m;
    __syncthreads();
    if (threadIdx.x == 0) {
        m = fmaxf(fmaxf(sm[0], sm[1]), fmaxf(sm[2], sm[3]));
        atomicMax(&maxbits[b], __float_as_uint(m));   // x>=0: bit cmp == fp cmp
    }
}

// ---------------- Kernel 2: fused normalize + block stats ----------------
// 64x32 tile, 30.4KB LDS -> 5 WG/CU (20 waves).
__global__ __launch_bounds__(256, 5) void piqe_main_kernel(
    const float* __restrict__ x, const unsigned int* __restrict__ maxbits,
    float* __restrict__ contrib_sum, unsigned int* __restrict__ nhsa)
{
    __shared__ float s_img[SR * SROW];   // 38x72; later MSCN n in-place
    __shared__ float s_m[SR * MROW];     // 38 rows x 32 float4 (mu,mu2 pairs)
    __shared__ float s_c;
    __shared__ unsigned int s_a;

    const int tid = threadIdx.x;
    const int b = blockIdx.z;
    const int ox = blockIdx.x * TW;
    const int oy = blockIdx.y * TH;
    const float* img0 = x + (size_t)b * (size_t)(IH * IW);
    const float scale = 255.0f / __uint_as_float(maxbits[b]);

    if (tid == 0) { s_c = 0.0f; s_a = 0u; }

    // ---- Phase A: stage tile. Interior: float4 global -> b128 LDS store
    // (L=4+4c: 8-lane phase groups sweep all 32 banks).
    {
        const int c = tid & 15;
        for (int r = tid >> 4; r < SR; r += 16) {
            int gy = oy + r - HALO; gy = max(0, min(IH - 1, gy));
            float4 vv = *(const float4*)(img0 + (size_t)gy * IW + ox + 4 * c);
            float4 w;
            w.x = rintf(vv.x * scale);
            w.y = rintf(vv.y * scale);
            w.z = rintf(vv.z * scale);
            w.w = rintf(vv.w * scale);
            *(float4*)&s_img[r * SROW + 4 + 4 * c] = w;
        }
        const int hc = tid & 7;                    // 6 halo cols, scalar
        if (hc < 6) {
            int Lc = (hc < 3) ? (1 + hc) : (65 + hc);           // 1,2,3,68,69,70
            int gx = (hc < 3) ? (ox - 3 + hc) : (ox + 61 + hc);
            gx = max(0, min(IW - 1, gx));
            for (int r = tid >> 3; r < SR; r += 32) {
                int gy = oy + r - HALO; gy = max(0, min(IH - 1, gy));
                s_img[r * SROW + Lc] = rintf(img0[(size_t)gy * IW + gx] * scale);
            }
        }
    }
    __syncthreads();

    const float gk[7] = {G0, G1, G2, G3, G2, G1, G0};

    // ---- Phase B: horizontal 7-tap (img, img^2) -> s_m interleaved.
    // 16 threads/row, 4 outputs each; 3 aligned b128 reads (full bank sweep).
    {
        const int c4 = (tid & 15) << 2;
        for (int r = tid >> 4; r < SR; r += 16) {
            const float* p = &s_img[r * SROW + c4];
            float v[12];
            *(float4*)(v)     = *(const float4*)(p);
            *(float4*)(v + 4) = *(const float4*)(p + 4);
            *(float4*)(v + 8) = *(const float4*)(p + 8);
            float q[11];
#pragma unroll
            for (int i = 1; i < 11; ++i) q[i] = v[i] * v[i];
            float om[4], om2[4];
#pragma unroll
            for (int j = 0; j < 4; ++j) {
                float m = 0.0f, m2 = 0.0f;
#pragma unroll
                for (int k = 0; k < 7; ++k) {
                    m  = fmaf(gk[k], v[1 + j + k], m);
                    m2 = fmaf(gk[k], q[1 + j + k], m2);
                }
                om[j] = m; om2[j] = m2;
            }
            float4 pa, pb;
            pa.x = om[0]; pa.y = om2[0]; pa.z = om[1]; pa.w = om2[1];
            pb.x = om[2]; pb.y = om2[2]; pb.z = om[3]; pb.w = om2[3];
            *(float4*)&s_m[r * MROW + 2 * c4]     = pa;
            *(float4*)&s_m[r * MROW + 2 * c4 + 4] = pb;
        }
    }
    __syncthreads();

    // ---- Phase C: vertical 7-tap, n = (img-mu)/(std+1) in-place in s_img.
    // thread = (col pair cp = tid&31, 4-row group); 10 b128 reads (bank sweep:
    // 4*cp spacing), float2 n-writes (16-lane b64 sweep). Disjoint pixels.
    {
        const int cp = tid & 31;
        const int r0 = (tid >> 5) * 4;
        float4 f[10];
#pragma unroll
        for (int i = 0; i < 10; ++i)
            f[i] = *(const float4*)&s_m[(r0 + i) * MROW + 4 * cp];
#pragma unroll
        for (int i = 0; i < 4; ++i) {
            float mA = 0.0f, m2A = 0.0f, mB = 0.0f, m2B = 0.0f;
#pragma unroll
            for (int k = 0; k < 7; ++k) {
                mA  = fmaf(gk[k], f[i + k].x, mA);
                m2A = fmaf(gk[k], f[i + k].y, m2A);
                mB  = fmaf(gk[k], f[i + k].z, mB);
                m2B = fmaf(gk[k], f[i + k].w, m2B);
            }
            float sdA = __builtin_amdgcn_sqrtf(fabsf(m2A - mA * mA));
            float sdB = __builtin_amdgcn_sqrtf(fabsf(m2B - mB * mB));
            int ii = (r0 + i + HALO) * SROW + 2 * cp + 4;
            float2 pix = *(float2*)&s_img[ii];
            float2 nn;
            nn.x = (pix.x - mA) * __builtin_amdgcn_rcpf(sdA + 1.0f);
            nn.y = (pix.y - mB) * __builtin_amdgcn_rcpf(sdB + 1.0f);
            *(float2*)&s_img[ii] = nn;
        }
    }
    __syncthreads();

    // ---- Phase D: per-16x16-block stats. 8 blocks; 32-lane team per block.
    {
        const int t = tid & 31;
        const int team = tid >> 5;             // 0..7
        const int bi = team >> 2, bj = team & 3;
        const int row = t >> 1, half = t & 1;
        const float* np0 = &s_img[(HALO + bi * 16) * SROW + (bj * 16 + 4)];
        const float* pr = np0 + row * SROW + half * 8;
        float rv[8];
        *(float4*)(rv)     = *(const float4*)(pr);
        *(float4*)(rv + 4) = *(const float4*)(pr + 4);
        float s1 = 0.0f, s2 = 0.0f;
#pragma unroll
        for (int k = 0; k < 8; ++k) { s1 += rv[k]; s2 += rv[k] * rv[k]; }
        float ce = half ? rv[0] : rv[7];       // center cols {7,8}
        float c1 = ce, c2 = ce * ce;
        float ex = half ? rv[1] : rv[7];       // sur excludes cols {7,9}
        float u1 = s1 - ex, u2 = s2 - ex * ex;

        // Edge 11-window seg-std minima: 44 evals spread over lanes 0..21 x2.
        float minstd = __builtin_inff();
        if (t < 22) {
#pragma unroll
            for (int rep = 0; rep < 2; ++rep) {
                int e = t + rep * 22;          // 0..43
                int edge = e / 11;             // 0..3 (const-div -> magic mul)
                int w = e - edge * 11;         // 0..10
                const float* q;
                int step;
                if (edge == 0)      { q = np0 + w;             step = 1;    }
                else if (edge == 1) { q = np0 + 15 * SROW + w; step = 1;    }
                else if (edge == 2) { q = np0 + w * SROW;      step = SROW; }
                else                { q = np0 + w * SROW + 15; step = SROW; }
                float a1 = 0.0f, a2 = 0.0f;
#pragma unroll
                for (int j = 0; j < 6; ++j) {
                    float v = q[j * step];
                    a1 += v;
                    a2 = fmaf(v, v, a2);
                }
                float var = (a2 - a1 * a1 * (1.0f / 6.0f)) * (1.0f / 5.0f);
                minstd = fminf(minstd,
                               __builtin_amdgcn_sqrtf(fmaxf(var, 0.0f)));
            }
        }

        // Butterfly reduction within each 32-lane team
#pragma unroll
        for (int m = 1; m < 32; m <<= 1) {
            s1 += __shfl_xor(s1, m);
            s2 += __shfl_xor(s2, m);
            c1 += __shfl_xor(c1, m);
            c2 += __shfl_xor(c2, m);
            u1 += __shfl_xor(u1, m);
            u2 += __shfl_xor(u2, m);
            minstd = fminf(minstd, __shfl_xor(minstd, m));
        }

        if (t == 0) {
            float bv = fmaxf((s2 - s1 * s1 * (1.0f / 256.0f)) * (1.0f / 255.0f), 0.0f);
            bool active = bv > ACT_TH;
            float cstd = __builtin_amdgcn_sqrtf(
                fmaxf((c2 - c1 * c1 * (1.0f / 32.0f)) * (1.0f / 31.0f), 0.0f));
            float sstd = __builtin_amdgcn_sqrtf(
                fmaxf((u2 - u1 * u1 * (1.0f / 224.0f)) * (1.0f / 223.0f), 0.0f));
            float csd = cstd / sstd;            // 0/0 -> NaN (matches ref)
            if (csd != csd) csd = 0.0f;
            float sigma = __builtin_amdgcn_sqrtf(bv);
            float beta = fabsf(sigma - csd) / fmaxf(sigma, csd);
            bool wnc = sigma > 2.0f * beta;     // NaN beta -> false (matches)
            bool impaired = minstd < IMP_TH;
            if (active) {
                float contrib = (impaired ? (1.0f - bv) : 0.0f) + (wnc ? bv : 0.0f);
                atomicAdd(&s_c, contrib);
                atomicAdd(&s_a, 1u);
            }
        }
    }
    __syncthreads();
    if (tid == 0) {
        atomicAdd(&contrib_sum[b], s_c);
        atomicAdd(&nhsa[b], s_a);
    }
}

// ---------------- Kernel 3: final score ----------------------------------
__global__ void piqe_finish_kernel(const float* __restrict__ contrib_sum,
                                   const unsigned int* __restrict__ nhsa,
                                   float* __restrict__ out)
{
    int b = threadIdx.x;
    if (b < NBATCH)
        out[b] = (contrib_sum[b] + 1.0f) / (1.0f + (float)nhsa[b]) * 100.0f;
}

extern "C" void kernel_launch(void* const* d_in, const int* in_sizes, int n_in,
                              void* d_out, int out_size, void* d_ws, size_t ws_size,
                              hipStream_t stream)
{
    const float* x = (const float*)d_in[0];
    float* out = (float*)d_out;

    unsigned int* maxbits = (unsigned int*)d_ws;                 // 8 u32 @ 0
    float* contrib = (float*)((char*)d_ws + 32);                 // 8 f32 @ 32
    unsigned int* nhsa = (unsigned int*)((char*)d_ws + 64);      // 8 u32 @ 64

    hipMemsetAsync(d_ws, 0, 96, stream);
    batch_max_kernel<<<dim3(256, NBATCH), 256, 0, stream>>>(x, maxbits);
    piqe_main_kernel<<<dim3(IW / TW, IH / TH, NBATCH), 256, 0, stream>>>(
        x, maxbits, contrib, nhsa);
    piqe_finish_kernel<<<1, 64, 0, stream>>>(contrib, nhsa, out);
}